// Round 1
// baseline (617.142 us; speedup 1.0000x reference)
//
#include <hip/hip_runtime.h>
#include <hip/hip_bf16.h>

#define B_SZ 256
#define S_LEN 512
#define NT 128
#define PAD 127
#define CHUNK 64          // emission steps staged per LDS chunk
#define RENORM_MASK 7     // renorm every 8 steps
#define RENORM_SHIFT 62   // multiply by 2^-62
#define LN2 0.69314718055994530942f

// ---------------- Denominator: linear-domain forward algorithm ----------------
// grid = 256 (one block per batch), block = 256 (j = tid&127 owns state j,
// h = tid>>7 splits the K (source-state) dimension in half).
__global__ __launch_bounds__(256) void crf_denom(
    const float* __restrict__ em,      // (B,S,T)
    const int*   __restrict__ tags,    // (B,S)
    const float* __restrict__ startT,  // (T)
    const float* __restrict__ endT,    // (T)
    const float* __restrict__ trans,   // (T,T)
    float* __restrict__ out)
{
    const int b   = blockIdx.x;
    const int tid = threadIdx.x;
    const int j   = tid & (NT - 1);
    const int h   = tid >> 7;          // 0 or 1

    __shared__ __align__(16) float alpha[NT];
    __shared__ __align__(16) float part[256];
    __shared__ float maskv[S_LEN];
    __shared__ __align__(16) float emb[CHUNK * NT];   // 32 KiB chunk of emissions

    const float* em_b = em + (size_t)b * S_LEN * NT;
    const int*   tg_b = tags + (size_t)b * S_LEN;

    // expT column-half in registers: col[k] = exp(trans[64h+k][j])
    float col[64];
    #pragma unroll
    for (int k = 0; k < 64; ++k)
        col[k] = __expf(trans[(64 * h + k) * NT + j]);

    // stage masks
    for (int q = tid; q < S_LEN; q += 256)
        maskv[q] = (tg_b[q] != PAD) ? 1.0f : 0.0f;

    // stage emission chunk 0 (t = 0..63)
    {
        const float4* src = (const float4*)em_b;
        float4* dst = (float4*)emb;
        #pragma unroll
        for (int q = 0; q < 8; ++q)
            dst[q * 256 + tid] = src[q * 256 + tid];
    }
    __syncthreads();

    float aj = 0.0f;   // state alpha_j (valid on h==0 threads)
    if (h == 0) {
        aj = __expf(startT[j] + emb[j]);
        alpha[j] = aj;
    }
    __syncthreads();

    for (int t = 1; t < S_LEN; ++t) {
        if ((t & (CHUNK - 1)) == 0) {
            // reload emission chunk [t, t+63]; prior sync guarantees old chunk consumed
            const float4* src = (const float4*)(em_b + (size_t)t * NT);
            float4* dst = (float4*)emb;
            #pragma unroll
            for (int q = 0; q < 8; ++q)
                dst[q * 256 + tid] = src[q * 256 + tid];
            __syncthreads();
        }

        // half-matvec: p = sum_{k} alpha[64h+k] * col[k]
        const float4* a4 = (const float4*)(alpha + 64 * h);
        float acc0 = 0.f, acc1 = 0.f, acc2 = 0.f, acc3 = 0.f;
        #pragma unroll
        for (int q = 0; q < 16; ++q) {
            float4 av = a4[q];
            acc0 += av.x * col[4 * q + 0];
            acc1 += av.y * col[4 * q + 1];
            acc2 += av.z * col[4 * q + 2];
            acc3 += av.w * col[4 * q + 3];
        }
        part[tid] = (acc0 + acc1) + (acc2 + acc3);
        __syncthreads();

        if (h == 0) {
            float e  = __expf(emb[(t & (CHUNK - 1)) * NT + j]);
            float nv = (part[j] + part[NT + j]) * e;
            float na = (maskv[t] != 0.0f) ? nv : aj;
            if ((t & RENORM_MASK) == 0) na *= 0x1p-62f;   // deterministic rescale
            aj = na;
            alpha[j] = na;
        }
        __syncthreads();
    }

    // denominator = c + log( sum_j alpha_j * exp(end_j) ), c = 63 * 62 * ln2
    if (h == 0)
        part[j] = aj * __expf(endT[j]);
    __syncthreads();

    if (tid < 64) {
        float s = part[tid] + part[tid + 64];
        #pragma unroll
        for (int o = 32; o > 0; o >>= 1)
            s += __shfl_down(s, o, 64);
        if (tid == 0) {
            float c = 63.0f * (float)RENORM_SHIFT * LN2;
            float den = c + logf(s);
            atomicAdd(out, -den * (1.0f / (float)B_SZ));
        }
    }
}

// ---------------- Numerator: gold-path score ----------------
__global__ __launch_bounds__(256) void crf_num(
    const float* __restrict__ em,
    const int*   __restrict__ tags,
    const float* __restrict__ startT,
    const float* __restrict__ endT,
    const float* __restrict__ trans,
    float* __restrict__ out)
{
    const int b   = blockIdx.x;
    const int tid = threadIdx.x;
    const int*   tg   = tags + (size_t)b * S_LEN;
    const float* em_b = em + (size_t)b * S_LEN * NT;

    __shared__ float red[256];
    __shared__ int   redi[256];

    float s = 0.0f;
    int cnt = 0;
    for (int t = tid; t < S_LEN; t += 256) {
        int tgt = tg[t];
        int m = (tgt != PAD) ? 1 : 0;
        cnt += m;
        if (t > 0) {
            int tgp = tg[t - 1];
            float v = trans[tgp * NT + tgt] + em_b[(size_t)t * NT + tgt];
            s += m ? v : 0.0f;
        } else {
            s += startT[tgt] + em_b[tgt];   // t=0 term, unmasked per reference
        }
    }
    red[tid] = s;
    redi[tid] = cnt;
    __syncthreads();
    if (tid < 128) { red[tid] += red[tid + 128]; redi[tid] += redi[tid + 128]; }
    __syncthreads();
    if (tid < 64) {
        float v = red[tid] + red[tid + 64];
        int   c = redi[tid] + redi[tid + 64];
        #pragma unroll
        for (int o = 32; o > 0; o >>= 1) {
            v += __shfl_down(v, o, 64);
            c += __shfl_down(c, o, 64);
        }
        if (tid == 0) {
            int last = tg[c - 1];
            float num = v + endT[last];
            atomicAdd(out, num * (1.0f / (float)B_SZ));
        }
    }
}

extern "C" void kernel_launch(void* const* d_in, const int* in_sizes, int n_in,
                              void* d_out, int out_size, void* d_ws, size_t ws_size,
                              hipStream_t stream) {
    const float* em     = (const float*)d_in[0];
    const int*   tags   = (const int*)d_in[1];
    const float* startT = (const float*)d_in[2];
    const float* endT   = (const float*)d_in[3];
    const float* trans  = (const float*)d_in[4];
    float* out = (float*)d_out;

    hipMemsetAsync(out, 0, sizeof(float), stream);
    crf_denom<<<B_SZ, 256, 0, stream>>>(em, tags, startT, endT, trans, out);
    crf_num  <<<B_SZ, 256, 0, stream>>>(em, tags, startT, endT, trans, out);
}

// Round 2
// 612.859 us; speedup vs baseline: 1.0070x; 1.0070x over previous
//
#include <hip/hip_runtime.h>
#include <hip/hip_bf16.h>

#define B_SZ 256
#define S_LEN 512
#define NT 128
#define PAD 127
#define LN2 0.69314718055994530942f
#define RENORM 0x1p-62f

typedef float v2f __attribute__((ext_vector_type(2)));

__device__ __forceinline__ float bcast(float v, int k) {
    return __uint_as_float((unsigned)__builtin_amdgcn_readlane((int)__float_as_uint(v), k));
}

// One wave per batch element. alpha (128 states) lives as 2 regs/lane
// (a0 = alpha[lane], a1 = alpha[lane+64]); exp(transitions) columns for
// j=lane and j=lane+64 live in 256 VGPRs. Broadcast of alpha[k] per step
// is v_readlane -> SGPR -> v_fma with SGPR operand. No LDS, no barriers.
__global__ __launch_bounds__(64, 1) void crf_fused(
    const float* __restrict__ em,      // (B,S,T)
    const int*   __restrict__ tags,    // (B,S)
    const float* __restrict__ startT,  // (T)
    const float* __restrict__ endT,    // (T)
    const float* __restrict__ trans,   // (T,T)
    float* __restrict__ out)
{
    const int b = blockIdx.x;
    const int l = threadIdx.x;                 // lane 0..63
    const float* em_b = em + (size_t)b * S_LEN * NT;
    const int*   tg_b = tags + (size_t)b * S_LEN;

    // ---- numerator gather + mask ballots (issued first; latency hidden by col init) ----
    unsigned long long mb[8];
    float numSum = 0.f;
    #pragma unroll
    for (int w = 0; w < 8; ++w) {
        int t  = 64 * w + l;
        int tv = tg_b[t];
        mb[w] = __ballot(tv != PAD);
        float emg = em_b[(size_t)t * NT + tv];
        if (t == 0) {
            numSum += startT[tv] + emg;
        } else {
            int tp = tg_b[t - 1];
            float v = trans[tp * NT + tv] + emg;
            numSum += (tv != PAD) ? v : 0.f;
        }
    }

    // ---- column registers: col[k] = (expT[k][l], expT[k][l+64]) ----
    v2f col[NT];
    #pragma unroll
    for (int k = 0; k < NT; ++k) {
        col[k].x = __expf(trans[k * NT + l]);
        col[k].y = __expf(trans[k * NT + 64 + l]);
    }

    // ---- alpha init (t = 0) ----
    float a0 = __expf(startT[l]      + em_b[l]);
    float a1 = __expf(startT[64 + l] + em_b[64 + l]);

    // raw emissions for t=1 (prefetched)
    float eR0 = em_b[1 * NT + l];
    float eR1 = em_b[1 * NT + 64 + l];

    #pragma unroll
    for (int w = 0; w < 8; ++w) {
        unsigned long long bits = mb[w];
        int i0 = (w == 0) ? 1 : 0;
        if (w == 0) bits >>= 1;
        #pragma unroll 2
        for (int i = i0; i < 64; ++i) {
            int t  = 64 * w + i;
            int tn = (t < S_LEN - 1) ? t + 1 : S_LEN - 1;
            // prefetch next step's raw emissions
            float eN0 = em_b[(size_t)tn * NT + l];
            float eN1 = em_b[(size_t)tn * NT + 64 + l];

            // matvec: acc = sum_k alpha[k] * col[k]   (4 acc pairs for ILP)
            v2f acc[4];
            acc[0] = (v2f){0.f, 0.f}; acc[1] = (v2f){0.f, 0.f};
            acc[2] = (v2f){0.f, 0.f}; acc[3] = (v2f){0.f, 0.f};
            #pragma unroll
            for (int k = 0; k < 64; ++k) {
                float s = bcast(a0, k);
                v2f sv = {s, s};
                acc[k & 3] += sv * col[k];
            }
            #pragma unroll
            for (int k = 0; k < 64; ++k) {
                float s = bcast(a1, k);
                v2f sv = {s, s};
                acc[k & 3] += sv * col[64 + k];
            }
            v2f accT = (acc[0] + acc[1]) + (acc[2] + acc[3]);

            float e0 = __expf(eR0);
            float e1 = __expf(eR1);
            float nv0 = accT.x * e0;
            float nv1 = accT.y * e1;

            if (bits & 1ull) { a0 = nv0; a1 = nv1; }   // mask (wave-uniform)
            bits >>= 1;
            if ((i & 7) == 0) { a0 *= RENORM; a1 *= RENORM; }  // deterministic rescale

            eR0 = eN0; eR1 = eN1;
        }
    }

    // ---- denominator: c + log( sum_j alpha_j * exp(end_j) ) ----
    float pe = a0 * __expf(endT[l]) + a1 * __expf(endT[64 + l]);
    #pragma unroll
    for (int off = 32; off > 0; off >>= 1) {
        pe     += __shfl_down(pe, off, 64);
        numSum += __shfl_down(numSum, off, 64);
    }

    if (l == 0) {
        int cnt = 0;
        #pragma unroll
        for (int w = 0; w < 8; ++w) cnt += __popcll(mb[w]);
        int   last = tg_b[cnt - 1];
        float num  = numSum + endT[last];
        float den  = 63.0f * 62.0f * LN2 + logf(pe);
        atomicAdd(out, (num - den) * (1.0f / (float)B_SZ));
    }
}

extern "C" void kernel_launch(void* const* d_in, const int* in_sizes, int n_in,
                              void* d_out, int out_size, void* d_ws, size_t ws_size,
                              hipStream_t stream) {
    const float* em     = (const float*)d_in[0];
    const int*   tags   = (const int*)d_in[1];
    const float* startT = (const float*)d_in[2];
    const float* endT   = (const float*)d_in[3];
    const float* trans  = (const float*)d_in[4];
    float* out = (float*)d_out;

    hipMemsetAsync(out, 0, sizeof(float), stream);
    crf_fused<<<B_SZ, 64, 0, stream>>>(em, tags, startT, endT, trans, out);
}

// Round 3
// 412.283 us; speedup vs baseline: 1.4969x; 1.4865x over previous
//
#include <hip/hip_runtime.h>
#include <hip/hip_bf16.h>

#define B_SZ 256
#define S_LEN 512
#define NT 128
#define PAD 127
#define LN2F 0.69314718055994530942f
#define RENORM 0x1p-62f

typedef float v2f __attribute__((ext_vector_type(2)));

__device__ __forceinline__ float bcastf(float v, int k) {
    return __uint_as_float((unsigned)__builtin_amdgcn_readlane((int)__float_as_uint(v), k));
}

// Barrier that drains only LDS (lgkmcnt), NOT vmcnt — keeps the emission
// prefetch ring in flight across steps (composable_kernel block_sync_lds idiom).
__device__ __forceinline__ void lds_barrier() {
    asm volatile("s_waitcnt lgkmcnt(0)\n\ts_barrier" ::: "memory");
}

// One block per batch element; 4 waves split the K (source state) dimension.
// Wave w holds exp(trans[k][:]) for k in [32w, 32w+32) as 32 v2f registers
// (64 VGPRs). alpha is replicated across waves: a.x = alpha[lane],
// a.y = alpha[lane+64]. Per step: 32 readlane broadcasts + 32 packed FMAs,
// then a 4-way partial-sum exchange through LDS (double-buffered, 1 barrier).
__global__ __launch_bounds__(256, 1) void crf_fused(
    const float* __restrict__ em,      // (B,S,T)
    const int*   __restrict__ tags,    // (B,S)
    const float* __restrict__ startT,  // (T)
    const float* __restrict__ endT,    // (T)
    const float* __restrict__ trans,   // (T,T)
    float* __restrict__ out)
{
    const int b   = blockIdx.x;
    const int tid = threadIdx.x;
    const int w   = tid >> 6;          // wave 0..3
    const int l   = tid & 63;          // lane

    __shared__ float buf[2][4][NT];    // [parity][wave][state]
    __shared__ float nred[4];

    const float* em_b = em + (size_t)b * S_LEN * NT;
    const int*   tg_b = tags + (size_t)b * S_LEN;

    // ---- mask ballots (every wave computes its own copy) ----
    unsigned long long mb[8];
    #pragma unroll
    for (int c = 0; c < 8; ++c) {
        int tv = tg_b[64 * c + l];
        mb[c] = __ballot(tv != PAD);
    }

    // ---- numerator partial: wave w covers chunks 2w and 2w+1 ----
    float numSum = 0.f;
    #pragma unroll
    for (int q = 0; q < 2; ++q) {
        int t  = 64 * (2 * w + q) + l;
        int tv = tg_b[t];
        float emg = em_b[(size_t)t * NT + tv];
        if (t == 0) {
            numSum += startT[tv] + emg;
        } else {
            int tp = tg_b[t - 1];
            float v = trans[tp * NT + tv] + emg;
            numSum += (tv != PAD) ? v : 0.f;
        }
    }

    // ---- column registers for this wave's K-slice ----
    const int k0 = 32 * w;
    v2f col[32];
    #pragma unroll
    for (int i = 0; i < 32; ++i) {
        col[i].x = __expf(trans[(k0 + i) * NT + l]);
        col[i].y = __expf(trans[(k0 + i) * NT + 64 + l]);
    }

    // ---- alpha init (t=0), replicated on all waves ----
    v2f a;
    a.x = __expf(startT[l]      + em_b[l]);
    a.y = __expf(startT[64 + l] + em_b[64 + l]);

    // ---- emission ring buffer: 8 steps of prefetch depth ----
    float er0[8], er1[8];
    #pragma unroll
    for (int t = 1; t <= 8; ++t) {
        er0[t & 7] = em_b[(size_t)t * NT + l];
        er1[t & 7] = em_b[(size_t)t * NT + 64 + l];
    }

    const bool useX = (w < 2);
    const int  base = (w & 1) * 32;

    #pragma unroll 8
    for (int t = 1; t < S_LEN; ++t) {
        const int par = t & 1;
        const int u   = t & 7;

        // this wave's broadcast source register: alpha[k0..k0+32) lives in
        // a.x (waves 0,1) or a.y (waves 2,3), lanes base..base+31
        float sreg = useX ? a.x : a.y;

        v2f acc0 = {0.f, 0.f}, acc1 = {0.f, 0.f}, acc2 = {0.f, 0.f}, acc3 = {0.f, 0.f};
        #pragma unroll
        for (int i = 0; i < 32; i += 4) {
            float s0 = bcastf(sreg, base + i);
            float s1 = bcastf(sreg, base + i + 1);
            float s2 = bcastf(sreg, base + i + 2);
            float s3 = bcastf(sreg, base + i + 3);
            v2f v0 = {s0, s0}, v1 = {s1, s1}, v2 = {s2, s2}, v3 = {s3, s3};
            acc0 += v0 * col[i];
            acc1 += v1 * col[i + 1];
            acc2 += v2 * col[i + 2];
            acc3 += v3 * col[i + 3];
        }
        v2f p = (acc0 + acc1) + (acc2 + acc3);

        // exchange partials
        buf[par][w][l]      = p.x;
        buf[par][w][l + 64] = p.y;

        // prefetch emissions for t+8 (stays in flight across the barrier)
        int tn = (t + 8 < S_LEN) ? t + 8 : S_LEN - 1;
        float pf0 = em_b[(size_t)tn * NT + l];
        float pf1 = em_b[(size_t)tn * NT + 64 + l];

        lds_barrier();

        float sx = (buf[par][0][l]      + buf[par][1][l])
                 + (buf[par][2][l]      + buf[par][3][l]);
        float sy = (buf[par][0][l + 64] + buf[par][1][l + 64])
                 + (buf[par][2][l + 64] + buf[par][3][l + 64]);

        float e0 = __expf(er0[u]);
        float e1 = __expf(er1[u]);
        er0[u] = pf0;
        er1[u] = pf1;

        float nvx = sx * e0;
        float nvy = sy * e1;

        bool upd = (mb[t >> 6] >> (t & 63)) & 1ull;   // wave-uniform
        if (upd) { a.x = nvx; a.y = nvy; }
        if ((t & 7) == 0) { a.x *= RENORM; a.y *= RENORM; }  // 63 renorms total
    }

    // ---- wrap-up: numerator partials to LDS, then wave 0 finishes ----
    #pragma unroll
    for (int off = 32; off > 0; off >>= 1)
        numSum += __shfl_down(numSum, off, 64);
    if (l == 0) nred[w] = numSum;
    lds_barrier();

    if (w == 0) {
        float pe = a.x * __expf(endT[l]) + a.y * __expf(endT[64 + l]);
        #pragma unroll
        for (int off = 32; off > 0; off >>= 1)
            pe += __shfl_down(pe, off, 64);
        if (l == 0) {
            int cnt = 0;
            #pragma unroll
            for (int c = 0; c < 8; ++c) cnt += __popcll(mb[c]);
            int   last = tg_b[cnt - 1];
            float num  = (nred[0] + nred[1]) + (nred[2] + nred[3]) + endT[last];
            float den  = 63.0f * 62.0f * LN2F + logf(pe);
            atomicAdd(out, (num - den) * (1.0f / (float)B_SZ));
        }
    }
}

extern "C" void kernel_launch(void* const* d_in, const int* in_sizes, int n_in,
                              void* d_out, int out_size, void* d_ws, size_t ws_size,
                              hipStream_t stream) {
    const float* em     = (const float*)d_in[0];
    const int*   tags   = (const int*)d_in[1];
    const float* startT = (const float*)d_in[2];
    const float* endT   = (const float*)d_in[3];
    const float* trans  = (const float*)d_in[4];
    float* out = (float*)d_out;

    hipMemsetAsync(out, 0, sizeof(float), stream);
    crf_fused<<<B_SZ, 256, 0, stream>>>(em, tags, startT, endT, trans, out);
}

// Round 4
// 271.979 us; speedup vs baseline: 2.2691x; 1.5159x over previous
//
#include <hip/hip_runtime.h>
#include <hip/hip_bf16.h>

#define B_SZ 256
#define S_LEN 512
#define NT 128
#define PAD 127
#define LN2F 0.69314718055994530942f
#define RENORM 0x1p-62f

typedef float v2f __attribute__((ext_vector_type(2)));

__device__ __forceinline__ float bcastf(float v, int k) {
    return __uint_as_float((unsigned)__builtin_amdgcn_readlane((int)__float_as_uint(v), k));
}

// Barrier draining only LDS (lgkmcnt), NOT vmcnt — emission prefetch loads
// stay in flight across steps.
__device__ __forceinline__ void lds_barrier() {
    asm volatile("s_waitcnt lgkmcnt(0)\n\ts_barrier" ::: "memory");
}

// One block per batch; 4 waves split K. Wave w holds exp(trans[k][:]) for
// k in [32w,32w+32) (64 VGPRs). alpha replicated per wave (a.x=alpha[lane],
// a.y=alpha[lane+64]). Emissions: 16 NAMED register slots (8-step software
// pipeline, no array indexing -> no forced vmcnt(0) materialization).
__global__ __launch_bounds__(256, 1) void crf_fused(
    const float* __restrict__ em,      // (B,S,T)
    const int*   __restrict__ tags,    // (B,S)
    const float* __restrict__ startT,  // (T)
    const float* __restrict__ endT,    // (T)
    const float* __restrict__ trans,   // (T,T)
    float* __restrict__ out)
{
    const int b   = blockIdx.x;
    const int tid = threadIdx.x;
    const int w   = tid >> 6;          // wave 0..3
    const int l   = tid & 63;          // lane

    __shared__ float buf[2][4][NT];    // [parity][wave][state]
    __shared__ float maskv[S_LEN];     // per-step mask as float
    __shared__ float nred[4];
    __shared__ int   cred[4];

    const float* em_b = em + (size_t)b * S_LEN * NT;
    const int*   tg_b = tags + (size_t)b * S_LEN;

    // ---- stage per-step masks ----
    for (int q = tid; q < S_LEN; q += 256)
        maskv[q] = (tg_b[q] != PAD) ? 1.0f : 0.0f;

    // ---- numerator partial + valid count (wave w covers chunks 2w, 2w+1) ----
    float numSum = 0.f;
    int   cnt    = 0;
    #pragma unroll
    for (int q = 0; q < 2; ++q) {
        int t  = 64 * (2 * w + q) + l;
        int tv = tg_b[t];
        cnt += (tv != PAD) ? 1 : 0;
        float emg = em_b[(size_t)t * NT + tv];
        if (t == 0) {
            numSum += startT[tv] + emg;
        } else {
            int tp = tg_b[t - 1];
            float v = trans[tp * NT + tv] + emg;
            numSum += (tv != PAD) ? v : 0.f;
        }
    }
    #pragma unroll
    for (int off = 32; off > 0; off >>= 1) {
        numSum += __shfl_down(numSum, off, 64);
        cnt    += __shfl_down(cnt, off, 64);
    }
    if (l == 0) { nred[w] = numSum; cred[w] = cnt; }

    // ---- column registers for this wave's K-slice ----
    const int k0 = 32 * w;
    v2f col[32];
    #pragma unroll
    for (int i = 0; i < 32; ++i) {
        col[i].x = __expf(trans[(k0 + i) * NT + l]);
        col[i].y = __expf(trans[(k0 + i) * NT + 64 + l]);
    }

    // ---- alpha init (t=0), replicated on all waves ----
    v2f a;
    a.x = __expf(startT[l]      + em_b[l]);
    a.y = __expf(startT[64 + l] + em_b[64 + l]);

    const bool useX = (w < 2);
    const int  base = (w & 1) * 32;

    // ---- named-register emission pipeline: slot s holds em for t = s+1 (mod 8) ----
    float rA0 = em_b[1 * NT + l], rB0 = em_b[1 * NT + 64 + l];
    float rA1 = em_b[2 * NT + l], rB1 = em_b[2 * NT + 64 + l];
    float rA2 = em_b[3 * NT + l], rB2 = em_b[3 * NT + 64 + l];
    float rA3 = em_b[4 * NT + l], rB3 = em_b[4 * NT + 64 + l];
    float rA4 = em_b[5 * NT + l], rB4 = em_b[5 * NT + 64 + l];
    float rA5 = em_b[6 * NT + l], rB5 = em_b[6 * NT + 64 + l];
    float rA6 = em_b[7 * NT + l], rB6 = em_b[7 * NT + 64 + l];
    float rA7 = em_b[8 * NT + l], rB7 = em_b[8 * NT + 64 + l];

    __syncthreads();   // maskv + nred visible; one-time full barrier

#define STEP(SL, T, RN)                                                      \
  {                                                                          \
    const int t_   = (T);                                                    \
    const int par_ = t_ & 1;                                                 \
    int   tn_ = (t_ + 8 < S_LEN) ? t_ + 8 : S_LEN - 1;                       \
    float nA_ = em_b[(size_t)tn_ * NT + l];                                  \
    float nB_ = em_b[(size_t)tn_ * NT + 64 + l];                             \
    float mv_ = maskv[t_];                                                   \
    float e0_ = __expf(rA##SL);                                              \
    float e1_ = __expf(rB##SL);                                              \
    rA##SL = nA_; rB##SL = nB_;                                              \
    float sreg_ = useX ? a.x : a.y;                                          \
    v2f a0_ = {0.f,0.f}, a1_ = {0.f,0.f}, a2_ = {0.f,0.f}, a3_ = {0.f,0.f};  \
    _Pragma("unroll")                                                        \
    for (int i_ = 0; i_ < 32; i_ += 4) {                                     \
      float s0_ = bcastf(sreg_, base + i_);                                  \
      float s1_ = bcastf(sreg_, base + i_ + 1);                              \
      float s2_ = bcastf(sreg_, base + i_ + 2);                              \
      float s3_ = bcastf(sreg_, base + i_ + 3);                              \
      a0_ += (v2f){s0_, s0_} * col[i_];                                      \
      a1_ += (v2f){s1_, s1_} * col[i_ + 1];                                  \
      a2_ += (v2f){s2_, s2_} * col[i_ + 2];                                  \
      a3_ += (v2f){s3_, s3_} * col[i_ + 3];                                  \
    }                                                                        \
    v2f p_ = (a0_ + a1_) + (a2_ + a3_);                                      \
    p_.x *= e0_;  p_.y *= e1_;          /* fold exp(em) into partial */      \
    buf[par_][w][l]      = p_.x;                                             \
    buf[par_][w][l + 64] = p_.y;                                             \
    lds_barrier();                                                           \
    float x0_ = buf[par_][0][l],      x1_ = buf[par_][1][l];                 \
    float x2_ = buf[par_][2][l],      x3_ = buf[par_][3][l];                 \
    float y0_ = buf[par_][0][l + 64], y1_ = buf[par_][1][l + 64];            \
    float y2_ = buf[par_][2][l + 64], y3_ = buf[par_][3][l + 64];            \
    float cx_ = (x0_ + x1_) + (x2_ + x3_);                                   \
    float cy_ = (y0_ + y1_) + (y2_ + y3_);                                   \
    bool  u_  = (mv_ != 0.0f);                                               \
    a.x = u_ ? cx_ : a.x;                                                    \
    a.y = u_ ? cy_ : a.y;                                                    \
    if (RN) { a.x *= RENORM; a.y *= RENORM; }                                \
  }

    // chunk 0: t = 1..7  (slot = (t-1)&7)
    STEP(0, 1, false) STEP(1, 2, false) STEP(2, 3, false) STEP(3, 4, false)
    STEP(4, 5, false) STEP(5, 6, false) STEP(6, 7, false)

    // chunks 1..63: t = 8c .. 8c+7 ; renorm at t = 8c (63 renorms total)
    for (int c = 1; c < 64; ++c) {
        const int t0 = c * 8;
        STEP(7, t0,     true)
        STEP(0, t0 + 1, false) STEP(1, t0 + 2, false) STEP(2, t0 + 3, false)
        STEP(3, t0 + 4, false) STEP(4, t0 + 5, false) STEP(5, t0 + 6, false)
        STEP(6, t0 + 7, false)
    }
#undef STEP

    // ---- finalize: wave 0 computes denominator and writes output ----
    if (w == 0) {
        float pe = a.x * __expf(endT[l]) + a.y * __expf(endT[64 + l]);
        #pragma unroll
        for (int off = 32; off > 0; off >>= 1)
            pe += __shfl_down(pe, off, 64);
        if (l == 0) {
            int   cT   = (cred[0] + cred[1]) + (cred[2] + cred[3]);
            int   last = tg_b[cT - 1];
            float num  = (nred[0] + nred[1]) + (nred[2] + nred[3]) + endT[last];
            float den  = 63.0f * 62.0f * LN2F + logf(pe);
            atomicAdd(out, (num - den) * (1.0f / (float)B_SZ));
        }
    }
}

extern "C" void kernel_launch(void* const* d_in, const int* in_sizes, int n_in,
                              void* d_out, int out_size, void* d_ws, size_t ws_size,
                              hipStream_t stream) {
    const float* em     = (const float*)d_in[0];
    const int*   tags   = (const int*)d_in[1];
    const float* startT = (const float*)d_in[2];
    const float* endT   = (const float*)d_in[3];
    const float* trans  = (const float*)d_in[4];
    float* out = (float*)d_out;

    hipMemsetAsync(out, 0, sizeof(float), stream);
    crf_fused<<<B_SZ, 256, 0, stream>>>(em, tags, startT, endT, trans, out);
}